// Round 2
// baseline (447.060 us; speedup 1.0000x reference)
//
#include <hip/hip_runtime.h>
#include <hip/hip_bf16.h>
#include <math.h>

#define NN 262144
#define NCC 65536

typedef __bf16 bf16x8 __attribute__((ext_vector_type(8)));
typedef float f32x4 __attribute__((ext_vector_type(4)));

// ---------- setup: blocks 0..47 precompute Mt; blocks 48..175 zero flags ----------
__global__ __launch_bounds__(256) void k_setup(const float* __restrict__ w_orig,
                                               const float* __restrict__ w_prop,
                                               const float* __restrict__ w_ctx,
                                               const float* __restrict__ W_fuse,
                                               __bf16* __restrict__ Mt,
                                               unsigned char* __restrict__ flags) {
    __shared__ float Wl[64 * 65];
    __shared__ float wl[64 * 65];
    int b = blockIdx.x;
    int t = threadIdx.x;
    if (b >= 48) {   // zero 2*NN flag bytes: 128 blocks * 256 threads * 16B
        ((uint4*)flags)[(b - 48) * 256 + t] = make_uint4(0u, 0u, 0u, 0u);
        return;
    }
    int seg = b >> 4, rem = b & 15;
    int ot = rem >> 2, mt = rem & 3;
    const float* wseg = seg == 0 ? w_orig : (seg == 1 ? w_prop : w_ctx);
    int to = (t & 15) * 4, tm = (t >> 4) * 4;
    float acc[4][4] = {};
    for (int kc = 0; kc < 4; ++kc) {
        __syncthreads();
        for (int i = 0; i < 16; ++i) {
            int f = i * 256 + t;
            int row = f >> 6, col = f & 63;
            Wl[row * 65 + col] = W_fuse[(size_t)(ot * 64 + row) * 768 + seg * 256 + kc * 64 + col];
            wl[row * 65 + col] = wseg[(size_t)(mt * 64 + row) * 256 + kc * 64 + col];
        }
        __syncthreads();
        for (int k = 0; k < 64; ++k) {
            float wo[4], wm2[4];
#pragma unroll
            for (int i = 0; i < 4; ++i) wo[i] = Wl[(to + i) * 65 + k];
#pragma unroll
            for (int j = 0; j < 4; ++j) wm2[j] = wl[(tm + j) * 65 + k];
#pragma unroll
            for (int i = 0; i < 4; ++i)
#pragma unroll
                for (int j = 0; j < 4; ++j) acc[i][j] += wo[i] * wm2[j];
        }
    }
    for (int i = 0; i < 4; ++i)
        for (int j = 0; j < 4; ++j) {
            int o = ot * 64 + to + i;
            int g = seg * 256 + mt * 64 + tm + j;
            Mt[(size_t)o * 768 + g] = (__bf16)acc[i][j];
        }
}

__global__ void k_setflags(const int* __restrict__ idxp, const int* __restrict__ idxc,
                           unsigned char* fp, unsigned char* fc) {
    int j = blockIdx.x * blockDim.x + threadIdx.x;
    if (j < NCC) { fp[idxp[j]] = 1; fc[idxc[j]] = 1; }
}

__device__ inline bf16x8 cvt8(f32x4 a, f32x4 b) {
    bf16x8 w;
    w[0] = (__bf16)a[0]; w[1] = (__bf16)a[1]; w[2] = (__bf16)a[2]; w[3] = (__bf16)a[3];
    w[4] = (__bf16)b[0]; w[5] = (__bf16)b[1]; w[6] = (__bf16)b[2]; w[7] = (__bf16)b[3];
    return w;
}

__device__ inline void do_copy(int bx, int wid, int lane,
                               const float* __restrict__ hp, const float* __restrict__ hc,
                               const unsigned char* __restrict__ fp,
                               const unsigned char* __restrict__ fc,
                               float* __restrict__ out0, float* __restrict__ out1) {
    int base = bx * 512 + wid * 64;          // 1024 blocks * 512 = 2*NN slots
    int tbl = base >= NN;                    // slab never straddles (NN % 64 == 0)
    const unsigned char* F = tbl ? fc : fp;
    const float* S = tbl ? hc : hp;
    float* D = tbl ? out1 : out0;
    int r0 = tbl ? base - NN : base;
    for (int i = 0; i < 64; ++i) {
        int r = r0 + i;
        if (!F[r]) {
            const float* s = S + (size_t)r * 256 + lane * 4;
            float* d = D + (size_t)r * 256 + lane * 4;
            *(f32x4*)d = *(const f32x4*)s;
        }
    }
}

// ---------- fused: barrier-free gathered GEMM (64x256 tile) + epilogue scatter + slab copy ----------
__global__ __launch_bounds__(512) void k_fused(const float* __restrict__ hp,
                                               const float* __restrict__ hc,
                                               const float* __restrict__ horig,
                                               const __bf16* __restrict__ Mt,
                                               const float* __restrict__ bfuse,
                                               const float* __restrict__ bias,
                                               const int* __restrict__ idxp,
                                               const int* __restrict__ idxc,
                                               const unsigned char* __restrict__ fp,
                                               const unsigned char* __restrict__ fc,
                                               float* __restrict__ out0,
                                               float* __restrict__ out1) {
    int t = threadIdx.x;
    int lane = t & 63, wid = t >> 6;
    int wm = wid >> 2, wn = wid & 3;         // wave tile 32 rows x 64 cols
    int jbase = blockIdx.x * 64;
    int l15 = lane & 15, lq = lane >> 4;

    int copyFirst = blockIdx.x & 1;          // half the blocks stream copy first -> per-CU overlap
    if (copyFirst) do_copy(blockIdx.x, wid, lane, hp, hc, fp, fc, out0, out1);

    // two A-row indices per lane (mi = 0,1)
    int j0 = jbase + wm * 32 + l15;
    int j1 = j0 + 16;
    int ip0 = idxp[j0], ip1 = idxp[j1];
    int ic0 = idxc[j0], ic1 = idxc[j1];

    // B row base pointers (per-lane fixed output column), k-offset lq*8 baked in
    const __bf16* bp0 = Mt + (size_t)(wn * 64 + 0  + l15) * 768 + lq * 8;
    const __bf16* bp1 = Mt + (size_t)(wn * 64 + 16 + l15) * 768 + lq * 8;
    const __bf16* bp2 = Mt + (size_t)(wn * 64 + 32 + l15) * 768 + lq * 8;
    const __bf16* bp3 = Mt + (size_t)(wn * 64 + 48 + l15) * 768 + lq * 8;

    f32x4 acc[2][4] = {};

#pragma unroll
    for (int seg = 0; seg < 3; ++seg) {
        const float* a0 = (seg == 0 ? horig + (size_t)j0 * 256
                          : seg == 1 ? hp + (size_t)ip0 * 256
                                     : hc + (size_t)ic0 * 256) + lq * 8;
        const float* a1 = (seg == 0 ? horig + (size_t)j1 * 256
                          : seg == 1 ? hp + (size_t)ip1 * 256
                                     : hc + (size_t)ic1 * 256) + lq * 8;
#pragma unroll
        for (int cc = 0; cc < 4; ++cc) {
            int c = seg * 4 + cc;
#pragma unroll
            for (int ks = 0; ks < 2; ++ks) {
                int aoff = cc * 64 + ks * 32;          // f32 elements
                int boff = c * 64 + ks * 32;           // bf16 elements
                bf16x8 af0 = cvt8(*(const f32x4*)(a0 + aoff), *(const f32x4*)(a0 + aoff + 4));
                bf16x8 af1 = cvt8(*(const f32x4*)(a1 + aoff), *(const f32x4*)(a1 + aoff + 4));
                bf16x8 b0 = *(const bf16x8*)(bp0 + boff);
                bf16x8 b1 = *(const bf16x8*)(bp1 + boff);
                bf16x8 b2 = *(const bf16x8*)(bp2 + boff);
                bf16x8 b3 = *(const bf16x8*)(bp3 + boff);
                acc[0][0] = __builtin_amdgcn_mfma_f32_16x16x32_bf16(af0, b0, acc[0][0], 0, 0, 0);
                acc[0][1] = __builtin_amdgcn_mfma_f32_16x16x32_bf16(af0, b1, acc[0][1], 0, 0, 0);
                acc[0][2] = __builtin_amdgcn_mfma_f32_16x16x32_bf16(af0, b2, acc[0][2], 0, 0, 0);
                acc[0][3] = __builtin_amdgcn_mfma_f32_16x16x32_bf16(af0, b3, acc[0][3], 0, 0, 0);
                acc[1][0] = __builtin_amdgcn_mfma_f32_16x16x32_bf16(af1, b0, acc[1][0], 0, 0, 0);
                acc[1][1] = __builtin_amdgcn_mfma_f32_16x16x32_bf16(af1, b1, acc[1][1], 0, 0, 0);
                acc[1][2] = __builtin_amdgcn_mfma_f32_16x16x32_bf16(af1, b2, acc[1][2], 0, 0, 0);
                acc[1][3] = __builtin_amdgcn_mfma_f32_16x16x32_bf16(af1, b3, acc[1][3], 0, 0, 0);
            }
        }
    }

    // epilogue: tanh(acc + b_fuse) + bias, scatter into both outputs
    float bfv[4], biv[4];
#pragma unroll
    for (int ni = 0; ni < 4; ++ni) {
        int o = wn * 64 + ni * 16 + l15;
        bfv[ni] = bfuse[o];
        biv[ni] = bias[o];
    }
#pragma unroll
    for (int mi = 0; mi < 2; ++mi) {
#pragma unroll
        for (int rr = 0; rr < 4; ++rr) {
            int j = jbase + wm * 32 + mi * 16 + lq * 4 + rr;
            int gp = idxp[j];
            int gc = idxc[j];
#pragma unroll
            for (int ni = 0; ni < 4; ++ni) {
                int o = wn * 64 + ni * 16 + l15;
                float v = tanhf(acc[mi][ni][rr] + bfv[ni]) + biv[ni];
                out0[(size_t)gp * 256 + o] = v;
                out1[(size_t)gc * 256 + o] = v;
            }
        }
    }

    if (!copyFirst) do_copy(blockIdx.x, wid, lane, hp, hc, fp, fc, out0, out1);
}

extern "C" void kernel_launch(void* const* d_in, const int* in_sizes, int n_in,
                              void* d_out, int out_size, void* d_ws, size_t ws_size,
                              hipStream_t stream) {
    const float* hp     = (const float*)d_in[0];
    const float* hc     = (const float*)d_in[1];
    const float* horig  = (const float*)d_in[2];
    const float* w_orig = (const float*)d_in[3];
    const float* w_prop = (const float*)d_in[4];
    const float* w_ctx  = (const float*)d_in[5];
    const float* W_fuse = (const float*)d_in[6];
    const float* bfuse  = (const float*)d_in[7];
    const float* bias   = (const float*)d_in[8];
    const int* idxp     = (const int*)d_in[9];
    const int* idxc     = (const int*)d_in[10];
    float* out0 = (float*)d_out;
    float* out1 = out0 + (size_t)NN * 256;

    char* ws = (char*)d_ws;
    __bf16* Mt = (__bf16*)ws;                              // 256*768*2 = 393216 B
    unsigned char* fp = (unsigned char*)(ws + 393216);     // NN bytes
    unsigned char* fc = fp + NN;                           // NN bytes

    k_setup<<<176, 256, 0, stream>>>(w_orig, w_prop, w_ctx, W_fuse, Mt, fp);
    k_setflags<<<NCC / 256, 256, 0, stream>>>(idxp, idxc, fp, fc);
    k_fused<<<1024, 512, 0, stream>>>(hp, hc, horig, Mt, bfuse, bias,
                                      idxp, idxc, fp, fc, out0, out1);
}

// Round 3
// 422.236 us; speedup vs baseline: 1.0588x; 1.0588x over previous
//
#include <hip/hip_runtime.h>
#include <hip/hip_bf16.h>
#include <math.h>

#define NN 262144
#define NCC 65536

typedef __bf16 bf16x8 __attribute__((ext_vector_type(8)));
typedef __bf16 bf16x4 __attribute__((ext_vector_type(4)));
typedef float f32x4 __attribute__((ext_vector_type(4)));

// ---------- setup: blocks 0..47 precompute Mt; blocks 48..175 zero flags ----------
__global__ __launch_bounds__(256) void k_setup(const float* __restrict__ w_orig,
                                               const float* __restrict__ w_prop,
                                               const float* __restrict__ w_ctx,
                                               const float* __restrict__ W_fuse,
                                               __bf16* __restrict__ Mt,
                                               unsigned char* __restrict__ flags) {
    __shared__ float Wl[64 * 65];
    __shared__ float wl[64 * 65];
    int b = blockIdx.x;
    int t = threadIdx.x;
    if (b >= 48) {   // zero 2*NN flag bytes: 128 blocks * 256 threads * 16B
        ((uint4*)flags)[(b - 48) * 256 + t] = make_uint4(0u, 0u, 0u, 0u);
        return;
    }
    int seg = b >> 4, rem = b & 15;
    int ot = rem >> 2, mt = rem & 3;
    const float* wseg = seg == 0 ? w_orig : (seg == 1 ? w_prop : w_ctx);
    int to = (t & 15) * 4, tm = (t >> 4) * 4;
    float acc[4][4] = {};
    for (int kc = 0; kc < 4; ++kc) {
        __syncthreads();
        for (int i = 0; i < 16; ++i) {
            int f = i * 256 + t;
            int row = f >> 6, col = f & 63;
            Wl[row * 65 + col] = W_fuse[(size_t)(ot * 64 + row) * 768 + seg * 256 + kc * 64 + col];
            wl[row * 65 + col] = wseg[(size_t)(mt * 64 + row) * 256 + kc * 64 + col];
        }
        __syncthreads();
        for (int k = 0; k < 64; ++k) {
            float wo[4], wm2[4];
#pragma unroll
            for (int i = 0; i < 4; ++i) wo[i] = Wl[(to + i) * 65 + k];
#pragma unroll
            for (int j = 0; j < 4; ++j) wm2[j] = wl[(tm + j) * 65 + k];
#pragma unroll
            for (int i = 0; i < 4; ++i)
#pragma unroll
                for (int j = 0; j < 4; ++j) acc[i][j] += wo[i] * wm2[j];
        }
    }
    for (int i = 0; i < 4; ++i)
        for (int j = 0; j < 4; ++j) {
            int o = ot * 64 + to + i;
            int g = seg * 256 + mt * 64 + tm + j;
            Mt[(size_t)o * 768 + g] = (__bf16)acc[i][j];
        }
}

__global__ void k_setflags(const int* __restrict__ idxp, const int* __restrict__ idxc,
                           unsigned char* fp, unsigned char* fc) {
    int j = blockIdx.x * blockDim.x + threadIdx.x;
    if (j < NCC) { fp[idxp[j]] = 1; fc[idxc[j]] = 1; }
}

__device__ inline void do_copy(int bx, int wid, int lane,
                               const float* __restrict__ hp, const float* __restrict__ hc,
                               const unsigned char* __restrict__ fp,
                               const unsigned char* __restrict__ fc,
                               float* __restrict__ out0, float* __restrict__ out1) {
    int base = bx * 256 + wid * 64;          // 2048 blocks * 256 = 2*NN slots
    int tbl = base >= NN;                    // slab never straddles (NN % 64 == 0)
    const unsigned char* F = tbl ? fc : fp;
    const float* S = tbl ? hc : hp;
    float* D = tbl ? out1 : out0;
    int r0 = tbl ? base - NN : base;
    for (int i = 0; i < 64; ++i) {
        int r = r0 + i;
        if (!F[r]) {
            const float* s = S + (size_t)r * 256 + lane * 4;
            float* d = D + (size_t)r * 256 + lane * 4;
            *(f32x4*)d = *(const f32x4*)s;
        }
    }
}

// ---------- fused: per-wave-LDS barrier-free gathered GEMM (32x256 tile) + scatter + slab copy ----------
__global__ __launch_bounds__(256, 4) void k_fused(const float* __restrict__ hp,
                                                  const float* __restrict__ hc,
                                                  const float* __restrict__ horig,
                                                  const __bf16* __restrict__ Mt,
                                                  const float* __restrict__ bfuse,
                                                  const float* __restrict__ bias,
                                                  const int* __restrict__ idxp,
                                                  const int* __restrict__ idxc,
                                                  const unsigned char* __restrict__ fp,
                                                  const unsigned char* __restrict__ fc,
                                                  float* __restrict__ out0,
                                                  float* __restrict__ out1) {
    __shared__ __bf16 Asmem[4 * 32 * 64];    // per-wave 4KB slice, 16KB total
    int t = threadIdx.x;
    int lane = t & 63, wid = t >> 6;
    int wn = wid;                            // wave tile: 32 rows x 64 cols
    int jbase = blockIdx.x * 32;
    int l15 = lane & 15, lq = lane >> 4;

    int copyFirst = blockIdx.x & 1;
    if (copyFirst) do_copy(blockIdx.x, wid, lane, hp, hc, fp, fc, out0, out1);

    __bf16* As = &Asmem[wid * 32 * 64];

    // B base pointers: per-lane output col (wn*64+ni*16+l15), k-offset lq*8 baked in
    const __bf16* bp[4];
#pragma unroll
    for (int ni = 0; ni < 4; ++ni)
        bp[ni] = Mt + (size_t)(wn * 64 + ni * 16 + l15) * 768 + lq * 8;

    f32x4 acc[2][4] = {};

    for (int seg = 0; seg < 3; ++seg) {
        // row pointers: staging row r = i*4 + lq, element slice l15*4
        const float* rp[8];
#pragma unroll
        for (int i = 0; i < 8; ++i) {
            int j = jbase + i * 4 + lq;
            const float* base = (seg == 0) ? horig + (size_t)j * 256
                              : (seg == 1) ? hp + (size_t)idxp[j] * 256
                                           : hc + (size_t)idxc[j] * 256;
            rp[i] = base + l15 * 4;
        }
#pragma unroll
        for (int cc = 0; cc < 4; ++cc) {
            // stage A chunk: 32 rows x 64 k, coalesced (4 rows x 256B per instr)
#pragma unroll
            for (int i = 0; i < 8; ++i) {
                f32x4 v = *(const f32x4*)(rp[i] + cc * 64);
                bf16x4 w;
                w[0] = (__bf16)v[0]; w[1] = (__bf16)v[1];
                w[2] = (__bf16)v[2]; w[3] = (__bf16)v[3];
                int r = i * 4 + lq;
                int boff = r * 128 + (((l15 >> 1) ^ (r & 7)) << 4) + (l15 & 1) * 8;
                *(bf16x4*)((char*)As + boff) = w;
            }
            // B fragment loads (global, L2-resident, imm-offset folded)
            bf16x8 bfr[4][2];
#pragma unroll
            for (int ni = 0; ni < 4; ++ni)
#pragma unroll
                for (int ks = 0; ks < 2; ++ks)
                    bfr[ni][ks] = *(const bf16x8*)(bp[ni] + (seg * 4 + cc) * 64 + ks * 32);
            // A fragment reads (swizzled, conflict-free)
            bf16x8 af[2][2];
#pragma unroll
            for (int mi = 0; mi < 2; ++mi)
#pragma unroll
                for (int ks = 0; ks < 2; ++ks) {
                    int rr = mi * 16 + l15;
                    int s = ks * 4 + lq;
                    af[mi][ks] = *(const bf16x8*)((char*)As + rr * 128 + ((s ^ (rr & 7)) << 4));
                }
#pragma unroll
            for (int mi = 0; mi < 2; ++mi)
#pragma unroll
                for (int ni = 0; ni < 4; ++ni)
#pragma unroll
                    for (int ks = 0; ks < 2; ++ks)
                        acc[mi][ni] = __builtin_amdgcn_mfma_f32_16x16x32_bf16(af[mi][ks], bfr[ni][ks], acc[mi][ni], 0, 0, 0);
        }
    }

    // epilogue: tanh(acc + b_fuse) + bias, scatter into both outputs
    float bfv[4], biv[4];
#pragma unroll
    for (int ni = 0; ni < 4; ++ni) {
        int o = wn * 64 + ni * 16 + l15;
        bfv[ni] = bfuse[o];
        biv[ni] = bias[o];
    }
#pragma unroll
    for (int mi = 0; mi < 2; ++mi) {
#pragma unroll
        for (int rr = 0; rr < 4; ++rr) {
            int j = jbase + mi * 16 + lq * 4 + rr;
            int gp = idxp[j];
            int gc = idxc[j];
#pragma unroll
            for (int ni = 0; ni < 4; ++ni) {
                int o = wn * 64 + ni * 16 + l15;
                float v = tanhf(acc[mi][ni][rr] + bfv[ni]) + biv[ni];
                out0[(size_t)gp * 256 + o] = v;
                out1[(size_t)gc * 256 + o] = v;
            }
        }
    }

    if (!copyFirst) do_copy(blockIdx.x, wid, lane, hp, hc, fp, fc, out0, out1);
}

extern "C" void kernel_launch(void* const* d_in, const int* in_sizes, int n_in,
                              void* d_out, int out_size, void* d_ws, size_t ws_size,
                              hipStream_t stream) {
    const float* hp     = (const float*)d_in[0];
    const float* hc     = (const float*)d_in[1];
    const float* horig  = (const float*)d_in[2];
    const float* w_orig = (const float*)d_in[3];
    const float* w_prop = (const float*)d_in[4];
    const float* w_ctx  = (const float*)d_in[5];
    const float* W_fuse = (const float*)d_in[6];
    const float* bfuse  = (const float*)d_in[7];
    const float* bias   = (const float*)d_in[8];
    const int* idxp     = (const int*)d_in[9];
    const int* idxc     = (const int*)d_in[10];
    float* out0 = (float*)d_out;
    float* out1 = out0 + (size_t)NN * 256;

    char* ws = (char*)d_ws;
    __bf16* Mt = (__bf16*)ws;                              // 256*768*2 = 393216 B
    unsigned char* fp = (unsigned char*)(ws + 393216);     // NN bytes
    unsigned char* fc = fp + NN;                           // NN bytes

    k_setup<<<176, 256, 0, stream>>>(w_orig, w_prop, w_ctx, W_fuse, Mt, fp);
    k_setflags<<<NCC / 256, 256, 0, stream>>>(idxp, idxc, fp, fc);
    k_fused<<<2048, 256, 0, stream>>>(hp, hc, horig, Mt, bfuse, bias,
                                      idxp, idxc, fp, fc, out0, out1);
}

// Round 4
// 323.708 us; speedup vs baseline: 1.3811x; 1.3044x over previous
//
#include <hip/hip_runtime.h>
#include <hip/hip_bf16.h>
#include <math.h>

#define NN 262144
#define NCC 65536

typedef __bf16 bf16x8 __attribute__((ext_vector_type(8)));
typedef float f32x4 __attribute__((ext_vector_type(4)));

// ---------- setup: blocks 0..47 precompute Mt; blocks 48..175 zero flags ----------
__global__ __launch_bounds__(256) void k_setup(const float* __restrict__ w_orig,
                                               const float* __restrict__ w_prop,
                                               const float* __restrict__ w_ctx,
                                               const float* __restrict__ W_fuse,
                                               __bf16* __restrict__ Mt,
                                               unsigned char* __restrict__ flags) {
    __shared__ float Wl[64 * 65];
    __shared__ float wl[64 * 65];
    int b = blockIdx.x;
    int t = threadIdx.x;
    if (b >= 48) {   // zero 2*NN flag bytes: 128 blocks * 256 threads * 16B
        ((uint4*)flags)[(b - 48) * 256 + t] = make_uint4(0u, 0u, 0u, 0u);
        return;
    }
    int seg = b >> 4, rem = b & 15;
    int ot = rem >> 2, mt = rem & 3;
    const float* wseg = seg == 0 ? w_orig : (seg == 1 ? w_prop : w_ctx);
    int to = (t & 15) * 4, tm = (t >> 4) * 4;
    float acc[4][4] = {};
    for (int kc = 0; kc < 4; ++kc) {
        __syncthreads();
        for (int i = 0; i < 16; ++i) {
            int f = i * 256 + t;
            int row = f >> 6, col = f & 63;
            Wl[row * 65 + col] = W_fuse[(size_t)(ot * 64 + row) * 768 + seg * 256 + kc * 64 + col];
            wl[row * 65 + col] = wseg[(size_t)(mt * 64 + row) * 256 + kc * 64 + col];
        }
        __syncthreads();
        for (int k = 0; k < 64; ++k) {
            float wo[4], wm2[4];
#pragma unroll
            for (int i = 0; i < 4; ++i) wo[i] = Wl[(to + i) * 65 + k];
#pragma unroll
            for (int j = 0; j < 4; ++j) wm2[j] = wl[(tm + j) * 65 + k];
#pragma unroll
            for (int i = 0; i < 4; ++i)
#pragma unroll
                for (int j = 0; j < 4; ++j) acc[i][j] += wo[i] * wm2[j];
        }
    }
    for (int i = 0; i < 4; ++i)
        for (int j = 0; j < 4; ++j) {
            int o = ot * 64 + to + i;
            int g = seg * 256 + mt * 64 + tm + j;
            Mt[(size_t)o * 768 + g] = (__bf16)acc[i][j];
        }
}

__global__ void k_setflags(const int* __restrict__ idxp, const int* __restrict__ idxc,
                           unsigned char* fp, unsigned char* fc) {
    int j = blockIdx.x * blockDim.x + threadIdx.x;
    if (j < NCC) { fp[idxp[j]] = 1; fc[idxc[j]] = 1; }
}

__device__ inline bf16x8 cvt8(f32x4 a, f32x4 b) {
    bf16x8 w;
    w[0] = (__bf16)a[0]; w[1] = (__bf16)a[1]; w[2] = (__bf16)a[2]; w[3] = (__bf16)a[3];
    w[4] = (__bf16)b[0]; w[5] = (__bf16)b[1]; w[6] = (__bf16)b[2]; w[7] = (__bf16)b[3];
    return w;
}

// ---------- gathered GEMM, 64x256 tile, 8 waves, reg-double-buffered staging ----------
__global__ __launch_bounds__(512, 4) void k_gemm(const float* __restrict__ hp,
                                                 const float* __restrict__ hc,
                                                 const float* __restrict__ horig,
                                                 const __bf16* __restrict__ Mt,
                                                 const float* __restrict__ bfuse,
                                                 const float* __restrict__ bias,
                                                 const int* __restrict__ idxp,
                                                 const int* __restrict__ idxc,
                                                 float* __restrict__ out0,
                                                 float* __restrict__ out1) {
    __shared__ __bf16 Al[64 * 64];    // 8KB, swizzled
    __shared__ __bf16 Bl[256 * 64];   // 32KB, swizzled
    int t = threadIdx.x;
    int jbase = blockIdx.x * 64;
    int lane = t & 63, wid = t >> 6;
    int wm = wid >> 2, wn = wid & 3;
    int l15 = lane & 15, lq = lane >> 4;

    // A staging: thread -> (row ar, 8-f32 slot aslot)
    int ar = t >> 3, aslot = t & 7;
    int jr = jbase + ar;
    const float* rowp0 = horig + (size_t)jr * 256 + aslot * 8;
    const float* rowp1 = hp + (size_t)idxp[jr] * 256 + aslot * 8;
    const float* rowp2 = hc + (size_t)idxc[jr] * 256 + aslot * 8;

    // B staging: thread -> (row bo, 32-elem half bkp)
    int bo = t >> 1, bkp = t & 1;
    const __bf16* bsrc = Mt + (size_t)bo * 768 + bkp * 32;

    f32x4 acc[2][4] = {};

    // prologue: load chunk 0
    f32x4 va0 = *(const f32x4*)(rowp0);
    f32x4 va1 = *(const f32x4*)(rowp0 + 4);
    bf16x8 vb[4];
#pragma unroll
    for (int i = 0; i < 4; ++i) vb[i] = *(const bf16x8*)(bsrc + i * 8);

#pragma unroll
    for (int c = 0; c < 12; ++c) {
        __syncthreads();   // previous compute done; safe to overwrite LDS
        // write staged regs to LDS
        *(bf16x8*)&Al[ar * 64 + ((aslot ^ (ar & 7)) << 3)] = cvt8(va0, va1);
#pragma unroll
        for (int i = 0; i < 4; ++i) {
            int slot = bkp * 4 + i;
            *(bf16x8*)&Bl[bo * 64 + ((slot ^ (bo & 7)) << 3)] = vb[i];
        }
        // issue next chunk's loads (latency hides under compute below)
        if (c < 11) {
            int cn = c + 1;
            int seg = cn >> 2, ko = (cn & 3) * 64;
            const float* s = (seg == 0 ? rowp0 : (seg == 1 ? rowp1 : rowp2)) + ko;
            va0 = *(const f32x4*)(s);
            va1 = *(const f32x4*)(s + 4);
#pragma unroll
            for (int i = 0; i < 4; ++i) vb[i] = *(const bf16x8*)(bsrc + cn * 64 + i * 8);
        }
        __syncthreads();
        // compute chunk c
#pragma unroll
        for (int ks = 0; ks < 2; ++ks) {
            bf16x8 af[2], bfr[4];
            int kslot = ks * 4 + lq;
#pragma unroll
            for (int mi = 0; mi < 2; ++mi) {
                int r = wm * 32 + mi * 16 + l15;
                af[mi] = *(const bf16x8*)&Al[r * 64 + ((kslot ^ (r & 7)) << 3)];
            }
#pragma unroll
            for (int ni = 0; ni < 4; ++ni) {
                int o = wn * 64 + ni * 16 + l15;
                bfr[ni] = *(const bf16x8*)&Bl[o * 64 + ((kslot ^ (o & 7)) << 3)];
            }
#pragma unroll
            for (int mi = 0; mi < 2; ++mi)
#pragma unroll
                for (int ni = 0; ni < 4; ++ni)
                    acc[mi][ni] = __builtin_amdgcn_mfma_f32_16x16x32_bf16(af[mi], bfr[ni], acc[mi][ni], 0, 0, 0);
        }
    }

    // epilogue: tanh(acc + b_fuse) + bias, scatter rows into both outputs
    float bfv[4], biv[4];
#pragma unroll
    for (int ni = 0; ni < 4; ++ni) {
        int o = wn * 64 + ni * 16 + l15;
        bfv[ni] = bfuse[o];
        biv[ni] = bias[o];
    }
#pragma unroll
    for (int mi = 0; mi < 2; ++mi) {
#pragma unroll
        for (int rr = 0; rr < 4; ++rr) {
            int j = jbase + wm * 32 + mi * 16 + lq * 4 + rr;
            int gp = idxp[j];
            int gc = idxc[j];
#pragma unroll
            for (int ni = 0; ni < 4; ++ni) {
                int o = wn * 64 + ni * 16 + l15;
                float v = tanhf(acc[mi][ni][rr] + bfv[ni]) + biv[ni];
                out0[(size_t)gp * 256 + o] = v;
                out1[(size_t)gc * 256 + o] = v;
            }
        }
    }
}

// ---------- masked copy: per-thread independent items, branch-free loads ----------
__global__ __launch_bounds__(256) void k_copy(const float* __restrict__ hp,
                                              const float* __restrict__ hc,
                                              const unsigned char* __restrict__ fp,
                                              const unsigned char* __restrict__ fc,
                                              float* __restrict__ out0,
                                              float* __restrict__ out1) {
    int tid = blockIdx.x * 256 + threadIdx.x;       // 1,048,576 threads
    const int stride = 4096 * 256;
#pragma unroll
    for (int it = 0; it < 32; ++it) {
        int gid = it * stride + tid;                // < 2*NN*64 = 33.5M
        int row = gid >> 6, slot = gid & 63;
        int tbl = row >= NN;
        int r = tbl ? row - NN : row;
        const unsigned char* F = tbl ? fc : fp;
        const float* S = tbl ? hc : hp;
        float* D = tbl ? out1 : out0;
        unsigned char f = F[r];
        // flagged rows: redirect read to row 0 (L1-resident) -> load stays unconditional
        const float* s = S + (size_t)(f ? 0 : r) * 256 + slot * 4;
        f32x4 v = *(const f32x4*)s;
        if (!f) *(f32x4*)(D + (size_t)r * 256 + slot * 4) = v;
    }
}

extern "C" void kernel_launch(void* const* d_in, const int* in_sizes, int n_in,
                              void* d_out, int out_size, void* d_ws, size_t ws_size,
                              hipStream_t stream) {
    const float* hp     = (const float*)d_in[0];
    const float* hc     = (const float*)d_in[1];
    const float* horig  = (const float*)d_in[2];
    const float* w_orig = (const float*)d_in[3];
    const float* w_prop = (const float*)d_in[4];
    const float* w_ctx  = (const float*)d_in[5];
    const float* W_fuse = (const float*)d_in[6];
    const float* bfuse  = (const float*)d_in[7];
    const float* bias   = (const float*)d_in[8];
    const int* idxp     = (const int*)d_in[9];
    const int* idxc     = (const int*)d_in[10];
    float* out0 = (float*)d_out;
    float* out1 = out0 + (size_t)NN * 256;

    char* ws = (char*)d_ws;
    __bf16* Mt = (__bf16*)ws;                              // 256*768*2 = 393216 B
    unsigned char* fp = (unsigned char*)(ws + 393216);     // NN bytes
    unsigned char* fc = fp + NN;                           // NN bytes

    k_setup<<<176, 256, 0, stream>>>(w_orig, w_prop, w_ctx, W_fuse, Mt, fp);
    k_setflags<<<NCC / 256, 256, 0, stream>>>(idxp, idxc, fp, fc);
    k_gemm<<<NCC / 64, 512, 0, stream>>>(hp, hc, horig, Mt, bfuse, bias,
                                         idxp, idxc, out0, out1);
    k_copy<<<4096, 256, 0, stream>>>(hp, hc, fp, fc, out0, out1);
}